// Round 1
// baseline (177.926 us; speedup 1.0000x reference)
//
#include <hip/hip_runtime.h>
#include <hip/hip_bf16.h>

#define S_LEN 2048
#define NHEAD 16
#define HDIM 64
#define HID 1024
#define BATCH 2

typedef __attribute__((ext_vector_type(8))) short s16x8;
typedef __attribute__((ext_vector_type(4))) short s16x4;
typedef __attribute__((ext_vector_type(4))) float f32x4;

__device__ __forceinline__ short f2bf(float f) {
    union { __hip_bfloat16 b; short s; } u;
    u.b = __float2bfloat16(f);
    return u.s;
}
__device__ __forceinline__ unsigned pack2bf(float a, float b) {
    unsigned lo = (unsigned short)f2bf(a);
    unsigned hi = (unsigned short)f2bf(b);
    return lo | (hi << 16);
}
__device__ __forceinline__ f32x4 mfma16(s16x8 a, s16x8 b, f32x4 c) {
    return __builtin_amdgcn_mfma_f32_16x16x32_bf16(a, b, c, 0, 0, 0);
}

// ---------------------------------------------------------------------------
// Kernel 1: fused QKV GEMM.  Y = x @ W.T  (W row-major [out,in], so both
// operands are k-contiguous).  M=4096, K=1024, fused N=3072 (wq|wk|wv).
// Q,K stored bf16 [b,h,s,d]; V stored TRANSPOSED bf16 [b,h,d,s].
// ---------------------------------------------------------------------------
__global__ __launch_bounds__(256) void qkv_gemm(
    const float* __restrict__ x, const float* __restrict__ wq,
    const float* __restrict__ wk, const float* __restrict__ wv,
    short* __restrict__ q_ws, short* __restrict__ k_ws, short* __restrict__ vt_ws)
{
    __shared__ short As[128][32];
    __shared__ short Bs[128][32];
    const int t = threadIdx.x;
    const int lane = t & 63, w = t >> 6;
    const int g = lane >> 4, r15 = lane & 15;
    const int wm = w >> 1, wn = w & 1;
    const int bid = blockIdx.x;
    const int mt = bid & 31, nt = bid >> 5;           // 32 x 24 blocks
    const int m0 = mt * 128, n0 = nt * 128;
    const int sel = n0 >> 10;                         // 0=q, 1=k, 2=v
    const float* W = (sel == 0) ? wq : ((sel == 1) ? wk : wv);
    const int nr0 = n0 & 1023;
    const int srow = t >> 3;                          // 0..31
    const int scol = (t & 7) * 4;                     // 0..28

    f32x4 acc[4][4] = {};

    for (int k0 = 0; k0 < 1024; k0 += 32) {
        __syncthreads();
        #pragma unroll
        for (int i = 0; i < 4; ++i) {
            int row = srow + i * 32;
            float4 va = *(const float4*)(x + (size_t)(m0 + row) * 1024 + k0 + scol);
            s16x4 sa = { f2bf(va.x), f2bf(va.y), f2bf(va.z), f2bf(va.w) };
            *(s16x4*)&As[row][scol] = sa;
            float4 vb = *(const float4*)(W + (size_t)(nr0 + row) * 1024 + k0 + scol);
            s16x4 sb = { f2bf(vb.x), f2bf(vb.y), f2bf(vb.z), f2bf(vb.w) };
            *(s16x4*)&Bs[row][scol] = sb;
        }
        __syncthreads();
        s16x8 af[4], bfr[4];
        #pragma unroll
        for (int mi = 0; mi < 4; ++mi)
            af[mi] = *(const s16x8*)&As[wm * 64 + mi * 16 + r15][g * 8];
        #pragma unroll
        for (int ni = 0; ni < 4; ++ni)
            bfr[ni] = *(const s16x8*)&Bs[wn * 64 + ni * 16 + r15][g * 8];
        #pragma unroll
        for (int mi = 0; mi < 4; ++mi)
            #pragma unroll
            for (int ni = 0; ni < 4; ++ni)
                acc[mi][ni] = mfma16(af[mi], bfr[ni], acc[mi][ni]);
    }

    // Epilogue: C/D layout col=lane&15, row=(lane>>4)*4+reg (m89/m91 verified)
    #pragma unroll
    for (int mi = 0; mi < 4; ++mi)
    #pragma unroll
    for (int ni = 0; ni < 4; ++ni) {
        f32x4 v = acc[mi][ni];
        #pragma unroll
        for (int reg = 0; reg < 4; ++reg) {
            int m  = m0 + wm * 64 + mi * 16 + g * 4 + reg;
            int ng = n0 + wn * 64 + ni * 16 + r15;
            int nn = ng & 1023;
            int b = m >> 11, s = m & 2047;
            int h = nn >> 6, d = nn & 63;
            short val = f2bf(v[reg]);
            if (sel == 0)
                q_ws[((size_t)(b * NHEAD + h) * S_LEN + s) * HDIM + d] = val;
            else if (sel == 1)
                k_ws[((size_t)(b * NHEAD + h) * S_LEN + s) * HDIM + d] = val;
            else
                vt_ws[((size_t)(b * NHEAD + h) * HDIM + d) * S_LEN + s] = val;
        }
    }
}

// ---------------------------------------------------------------------------
// Kernel 2: causal flash attention, one (b,h,q-tile of 64) per block.
// 4 waves x 16 q-rows.  Swapped QK^T: S^T = mfma(K, Q^T) so each lane owns
// one q-row (q = lane&15) and 16 keys -> in-register online softmax.
// PV as O^T = mfma(V^T, P^T) using the transposed V layout from kernel 1.
// ---------------------------------------------------------------------------
__global__ __launch_bounds__(256) void attn_kernel(
    const short* __restrict__ q_ws, const short* __restrict__ k_ws,
    const short* __restrict__ vt_ws, short* __restrict__ attn_ws)
{
    __shared__ short Ks[64][64];    // [key][d], XOR-swizzled
    __shared__ short Vts[64][64];   // [d][key], XOR-swizzled
    const int t = threadIdx.x;
    const int lane = t & 63;
    const int w = t >> 6;
    const int g = lane >> 4, r15 = lane & 15;
    const int bid = blockIdx.x;
    const int qt = bid & 31;
    const int bh = bid >> 5;                      // b*16+h
    const int q0 = qt * 64;
    const int qg = q0 + w * 16 + r15;             // this lane's q row
    const size_t bhbase = (size_t)bh * S_LEN * HDIM;

    s16x8 qf[2];
    #pragma unroll
    for (int c = 0; c < 2; ++c)
        qf[c] = *(const s16x8*)(q_ws + bhbase + (size_t)qg * HDIM + c * 32 + g * 8);

    f32x4 o[4] = {};
    float mrun = -1e30f, lrun = 0.f;

    for (int kt = 0; kt <= qt; ++kt) {
        const int kv0 = kt * 64;
        __syncthreads();
        // stage K tile [64][64] and Vt tile [64][64], swizzle col ^= (row&7)<<3
        #pragma unroll
        for (int i = 0; i < 2; ++i) {
            int off = (t + i * 256) * 8;
            int row = off >> 6;
            int col = off & 63;
            int colx = col ^ ((row & 7) << 3);
            *(s16x8*)&Ks[row][colx] =
                *(const s16x8*)(k_ws + bhbase + (size_t)(kv0 + row) * HDIM + col);
            *(s16x8*)&Vts[row][colx] =
                *(const s16x8*)(vt_ws + bhbase + (size_t)row * S_LEN + kv0 + col);
        }
        __syncthreads();

        // S^T frags: lane holds keys kv0 + f*16 + g*4 + reg for q = qg
        float p[4][4];
        float pmax = -1e30f;
        #pragma unroll
        for (int f = 0; f < 4; ++f) {
            int row = f * 16 + r15;
            int sw = (row & 7) << 3;
            s16x8 ka = *(const s16x8*)&Ks[row][(g * 8) ^ sw];
            s16x8 kb = *(const s16x8*)&Ks[row][(32 + g * 8) ^ sw];
            f32x4 z = { 0.f, 0.f, 0.f, 0.f };
            z = mfma16(ka, qf[0], z);
            z = mfma16(kb, qf[1], z);
            #pragma unroll
            for (int reg = 0; reg < 4; ++reg) {
                int key = kv0 + f * 16 + g * 4 + reg;
                float sv = z[reg] * 0.125f;
                sv = (key > qg) ? -1e30f : sv;
                p[f][reg] = sv;
                pmax = fmaxf(pmax, sv);
            }
        }
        // row max/sum live in 4 lane-groups with the same q -> reduce over g
        pmax = fmaxf(pmax, __shfl_xor(pmax, 16));
        pmax = fmaxf(pmax, __shfl_xor(pmax, 32));
        float newm = fmaxf(mrun, pmax);
        float sc = __expf(mrun - newm);
        float rsum = 0.f;
        unsigned pu[4][2];
        #pragma unroll
        for (int f = 0; f < 4; ++f) {
            float e0 = __expf(p[f][0] - newm);
            float e1 = __expf(p[f][1] - newm);
            float e2 = __expf(p[f][2] - newm);
            float e3 = __expf(p[f][3] - newm);
            rsum += (e0 + e1) + (e2 + e3);
            pu[f][0] = pack2bf(e0, e1);
            pu[f][1] = pack2bf(e2, e3);
        }
        rsum += __shfl_xor(rsum, 16);
        rsum += __shfl_xor(rsum, 32);
        lrun = lrun * sc + rsum;
        mrun = newm;
        #pragma unroll
        for (int f2 = 0; f2 < 4; ++f2) o[f2] *= sc;

        // Redistribute P into PV B-fragments:
        // slot (g,j) of chunk c needs key = 32c+8g+j, held at source lane
        // r15 + 16*(2*(g&1)+(j>>2)), frag 2c+(g>>1), reg j&3.
        const int hi = g >> 1;
        const int src0 = r15 + ((g & 1) << 5);
        const int src1 = src0 + 16;
        s16x8 pb[2];
        #pragma unroll
        for (int c = 0; c < 2; ++c) {
            unsigned a00 = (unsigned)__shfl((int)pu[2 * c][0], src0);
            unsigned a01 = (unsigned)__shfl((int)pu[2 * c][1], src0);
            unsigned a10 = (unsigned)__shfl((int)pu[2 * c][0], src1);
            unsigned a11 = (unsigned)__shfl((int)pu[2 * c][1], src1);
            unsigned b00 = (unsigned)__shfl((int)pu[2 * c + 1][0], src0);
            unsigned b01 = (unsigned)__shfl((int)pu[2 * c + 1][1], src0);
            unsigned b10 = (unsigned)__shfl((int)pu[2 * c + 1][0], src1);
            unsigned b11 = (unsigned)__shfl((int)pu[2 * c + 1][1], src1);
            union { s16x8 v; unsigned u[4]; } pc;
            pc.u[0] = hi ? b00 : a00;
            pc.u[1] = hi ? b01 : a01;
            pc.u[2] = hi ? b10 : a10;
            pc.u[3] = hi ? b11 : a11;
            pb[c] = pc.v;
        }

        // O^T += V^T * P^T : lane holds O[d = 16*f2 + 4g + reg][q = qg]
        #pragma unroll
        for (int f2 = 0; f2 < 4; ++f2) {
            int row = f2 * 16 + r15;
            int sw = (row & 7) << 3;
            s16x8 va = *(const s16x8*)&Vts[row][(g * 8) ^ sw];
            s16x8 vb = *(const s16x8*)&Vts[row][(32 + g * 8) ^ sw];
            o[f2] = mfma16(va, pb[0], o[f2]);
            o[f2] = mfma16(vb, pb[1], o[f2]);
        }
    }

    float inv = 1.f / (lrun + 1e-8f);
    const int b = bh >> 4, h = bh & 15;
    size_t obase = ((size_t)b * S_LEN + qg) * HID + h * HDIM + g * 4;
    #pragma unroll
    for (int f2 = 0; f2 < 4; ++f2) {
        s16x4 ov = { f2bf(o[f2][0] * inv), f2bf(o[f2][1] * inv),
                     f2bf(o[f2][2] * inv), f2bf(o[f2][3] * inv) };
        *(s16x4*)(attn_ws + obase + f2 * 16) = ov;
    }
}

// ---------------------------------------------------------------------------
// Kernel 3: out = attn(bf16) @ wo.T  -> fp32 d_out.  M=4096,N=1024,K=1024.
// ---------------------------------------------------------------------------
__global__ __launch_bounds__(256) void wo_gemm(
    const short* __restrict__ attn, const float* __restrict__ wo,
    float* __restrict__ out)
{
    __shared__ short As[128][32];
    __shared__ short Bs[128][32];
    const int t = threadIdx.x;
    const int lane = t & 63, w = t >> 6;
    const int g = lane >> 4, r15 = lane & 15;
    const int wm = w >> 1, wn = w & 1;
    const int bid = blockIdx.x;
    const int mt = bid & 31, nt = bid >> 5;            // 32 x 8 blocks
    const int m0 = mt * 128, n0 = nt * 128;
    const int arow = t >> 2, acol = (t & 3) * 8;
    const int srow = t >> 3, scol = (t & 7) * 4;

    f32x4 acc[4][4] = {};

    for (int k0 = 0; k0 < 1024; k0 += 32) {
        __syncthreads();
        #pragma unroll
        for (int i = 0; i < 2; ++i) {
            int row = arow + i * 64;
            *(s16x8*)&As[row][acol] =
                *(const s16x8*)(attn + (size_t)(m0 + row) * 1024 + k0 + acol);
        }
        #pragma unroll
        for (int i = 0; i < 4; ++i) {
            int row = srow + i * 32;
            float4 vb = *(const float4*)(wo + (size_t)(n0 + row) * 1024 + k0 + scol);
            s16x4 sb = { f2bf(vb.x), f2bf(vb.y), f2bf(vb.z), f2bf(vb.w) };
            *(s16x4*)&Bs[row][scol] = sb;
        }
        __syncthreads();
        s16x8 af[4], bfr[4];
        #pragma unroll
        for (int mi = 0; mi < 4; ++mi)
            af[mi] = *(const s16x8*)&As[wm * 64 + mi * 16 + r15][g * 8];
        #pragma unroll
        for (int ni = 0; ni < 4; ++ni)
            bfr[ni] = *(const s16x8*)&Bs[wn * 64 + ni * 16 + r15][g * 8];
        #pragma unroll
        for (int mi = 0; mi < 4; ++mi)
            #pragma unroll
            for (int ni = 0; ni < 4; ++ni)
                acc[mi][ni] = mfma16(af[mi], bfr[ni], acc[mi][ni]);
    }

    #pragma unroll
    for (int mi = 0; mi < 4; ++mi)
    #pragma unroll
    for (int ni = 0; ni < 4; ++ni) {
        #pragma unroll
        for (int reg = 0; reg < 4; ++reg) {
            int m = m0 + wm * 64 + mi * 16 + g * 4 + reg;
            int n = n0 + wn * 64 + ni * 16 + r15;
            out[(size_t)m * 1024 + n] = acc[mi][ni][reg];
        }
    }
}

extern "C" void kernel_launch(void* const* d_in, const int* in_sizes, int n_in,
                              void* d_out, int out_size, void* d_ws, size_t ws_size,
                              hipStream_t stream) {
    const float* x  = (const float*)d_in[0];
    const float* wq = (const float*)d_in[1];
    const float* wk = (const float*)d_in[2];
    const float* wv = (const float*)d_in[3];
    const float* wo = (const float*)d_in[4];
    float* out = (float*)d_out;

    const size_t ELEMS = (size_t)BATCH * S_LEN * HID;   // 4096*1024
    short* q_ws    = (short*)d_ws;
    short* k_ws    = q_ws + ELEMS;
    short* vt_ws   = k_ws + ELEMS;
    short* attn_ws = vt_ws + ELEMS;

    qkv_gemm<<<dim3(768), dim3(256), 0, stream>>>(x, wq, wk, wv, q_ws, k_ws, vt_ws);
    attn_kernel<<<dim3(1024), dim3(256), 0, stream>>>(q_ws, k_ws, vt_ws, attn_ws);
    wo_gemm<<<dim3(256), dim3(256), 0, stream>>>(attn_ws, wo, out);
}